// Round 1
// baseline (126.763 us; speedup 1.0000x reference)
//
#include <hip/hip_runtime.h>
#include <math.h>

#define SH_C0     0.28209479177387814f
#define EPS2D     0.3f
#define NEARZ     0.01f
#define ALPHA_MIN (1.0f/255.0f)
#define ALPHA_MAX 0.999f
#define LOG2E     1.4426950408889634f

#define SEGS   32   // total depth segments (4 layer-blocks x 8 waves)
#define LSEG   8    // segments (waves) per block
#define NLAYER 4    // layer-blocks per pixel group

// ---------------------------------------------------------------------------
// Fused preprocess + stable-rank + scatter. One 64-lane wave per gaussian.
// Record (12 floats, 48B, float4-aligned), NEW layout for tile culling:
//   rec[0] = {u, v, rx, ry}      bbox of the alpha>=1/255 ellipse (+margin)
//   rec[1] = {A2', B', C2', op}  sigma in log2 domain: A2'=0.5*conA*log2e ...
//   rec[2] = {cr, cg, cb, 0}
// Invisible gaussians (z<=NEAR, det<=0, or op<=1/255): all-zero record ->
// ry=0 fails the bbox test everywhere -> contributes exactly 0 alpha, same
// as the reference's clamp-to-zero. Rank key = (zc > NEAR ? zc : +inf) with
// stable ties, identical to the reference argsort order.
// Block 0 additionally zeroes the per-tile combine counters and the dummy
// record N (prefetch target for the render loop's last iteration).
// ---------------------------------------------------------------------------
__global__ __launch_bounds__(256) void prep_rank_kernel(
        const float* __restrict__ means,
        const float* __restrict__ quats,
        const float* __restrict__ scales,
        const float* __restrict__ opacities,
        const float* __restrict__ sh,
        const float* __restrict__ vm,
        const float* __restrict__ K,
        float* __restrict__ sorted,
        int* __restrict__ cnt,
        int N, int tiles) {
    // aux init (runs before render kernel by stream order)
    if (blockIdx.x == 0) {
        for (int t = threadIdx.x; t < tiles; t += 256) cnt[t] = 0;
        if (threadIdx.x < 12) sorted[12*(size_t)N + threadIdx.x] = 0.f;
    }

    int wave = blockIdx.x * 4 + (threadIdx.x >> 6);
    int lane = threadIdx.x & 63;
    if (wave >= N) return;
    int i = wave;

    float r00=vm[0], r01=vm[1], r02=vm[2],  t0=vm[3];
    float r10=vm[4], r11=vm[5], r12=vm[6],  t1=vm[7];
    float r20=vm[8], r21=vm[9], r22=vm[10], t2=vm[11];

    // --- stable rank: count keys strictly smaller (ties: j < i) ---
    float mx = means[3*i+0], my = means[3*i+1], mz = means[3*i+2];
    float zci = r20*mx + r21*my + r22*mz + t2;
    float keyi = (zci > NEARZ) ? zci : INFINITY;
    int cntk = 0;
    for (int j = lane; j < N; j += 64) {
        float ax = means[3*j+0], ay = means[3*j+1], az = means[3*j+2];
        float zcj = r20*ax + r21*ay + r22*az + t2;
        float keyj = (zcj > NEARZ) ? zcj : INFINITY;
        cntk += (keyj < keyi) || (keyj == keyi && j < i);
    }
    #pragma unroll
    for (int off = 32; off > 0; off >>= 1)
        cntk += __shfl_xor(cntk, off, 64);

    // --- preprocess (redundant across lanes; uniform loads) ---
    float qw = quats[4*i+0], qx = quats[4*i+1], qy = quats[4*i+2], qz = quats[4*i+3];
    float rqn = rsqrtf(qw*qw + qx*qx + qy*qy + qz*qz);
    qw *= rqn; qx *= rqn; qy *= rqn; qz *= rqn;

    float R00 = 1.f - 2.f*(qy*qy + qz*qz);
    float R01 = 2.f*(qx*qy - qw*qz);
    float R02 = 2.f*(qx*qz + qw*qy);
    float R10 = 2.f*(qx*qy + qw*qz);
    float R11 = 1.f - 2.f*(qx*qx + qz*qz);
    float R12 = 2.f*(qy*qz - qw*qx);
    float R20 = 2.f*(qx*qz - qw*qy);
    float R21 = 2.f*(qy*qz + qw*qx);
    float R22 = 1.f - 2.f*(qx*qx + qy*qy);

    float s0 = fminf(expf(scales[3*i+0]), 10.f);
    float s1 = fminf(expf(scales[3*i+1]), 10.f);
    float s2 = fminf(expf(scales[3*i+2]), 10.f);

    float M00=R00*s0, M01=R01*s1, M02=R02*s2;
    float M10=R10*s0, M11=R11*s1, M12=R12*s2;
    float M20=R20*s0, M21=R21*s1, M22=R22*s2;

    float c00 = M00*M00 + M01*M01 + M02*M02;
    float c01 = M00*M10 + M01*M11 + M02*M12;
    float c02 = M00*M20 + M01*M21 + M02*M22;
    float c11 = M10*M10 + M11*M11 + M12*M12;
    float c12 = M10*M20 + M11*M21 + M12*M22;
    float c22 = M20*M20 + M21*M21 + M22*M22;

    float xc = r00*mx + r01*my + r02*mz + t0;
    float yc = r10*mx + r11*my + r12*mz + t1;
    float zc = zci;

    float T00 = r00*c00 + r01*c01 + r02*c02;
    float T01 = r00*c01 + r01*c11 + r02*c12;
    float T02 = r00*c02 + r01*c12 + r02*c22;
    float T10 = r10*c00 + r11*c01 + r12*c02;
    float T11 = r10*c01 + r11*c11 + r12*c12;
    float T12 = r10*c02 + r11*c12 + r12*c22;
    float T20 = r20*c00 + r21*c01 + r22*c02;
    float T21 = r20*c01 + r21*c11 + r22*c12;
    float T22 = r20*c02 + r21*c12 + r22*c22;
    float V00 = T00*r00 + T01*r01 + T02*r02;
    float V01 = T00*r10 + T01*r11 + T02*r12;
    float V02 = T00*r20 + T01*r21 + T02*r22;
    float V11 = T10*r10 + T11*r11 + T12*r12;
    float V12 = T10*r20 + T11*r21 + T12*r22;
    float V22 = T20*r20 + T21*r21 + T22*r22;

    float fx = K[0], cx = K[2], fy = K[4], cy = K[5];

    bool valid = zc > NEARZ;
    float zs = valid ? zc : 1.0f;
    float rz = 1.0f / zs;
    float u = fx*xc*rz + cx;
    float v = fy*yc*rz + cy;
    float J00 = fx*rz;
    float J02 = -fx*xc*rz*rz;
    float J11 = fy*rz;
    float J12 = -fy*yc*rz*rz;

    float a = J00*J00*V00 + 2.f*J00*J02*V02 + J02*J02*V22 + EPS2D;
    float b = J00*(J11*V01 + J12*V02) + J02*(J11*V12 + J12*V22);
    float c = J11*J11*V11 + 2.f*J11*J12*V12 + J12*J12*V22 + EPS2D;
    float det = a*c - b*b;
    valid = valid && (det > 0.f);
    float det_s = valid ? det : 1.0f;
    float conA =  c / det_s;
    float conB = -b / det_s;
    float conC =  a / det_s;

    float op  = 1.0f / (1.0f + expf(-opacities[i]));
    float cr = fmaxf(sh[3*i+0]*SH_C0 + 0.5f, 0.f);
    float cg = fmaxf(sh[3*i+1]*SH_C0 + 0.5f, 0.f);
    float cb = fmaxf(sh[3*i+2]*SH_C0 + 0.5f, 0.f);

    // bbox of {alpha >= 1/255}: q(dx,dy) = A2'dx^2 + B'dxdy + C2'dy^2 <= qmax
    //   rx = sqrt(qmax*C2'/det2), ry = sqrt(qmax*A2'/det2),
    //   det2 = A2'*C2' - B'^2/4 = log2e^2/(4*det) > 0 when valid.
    float e0=0,e1=0,eA=0,eB=0,eC=0,eOp=0,eR=0,eG=0,eBc=0,rx=0,ry=0;
    if (valid) {
        float qmax = log2f(op * 255.f);
        if (qmax > 0.f) {
            float a2 = 0.5f*conA*LOG2E;
            float b2 = conB*LOG2E;
            float c2 = 0.5f*conC*LOG2E;
            float det2 = a2*c2 - 0.25f*b2*b2;
            float inv = qmax / det2;
            rx = sqrtf(c2 * inv) * 1.0001f + 0.01f;
            ry = sqrtf(a2 * inv) * 1.0001f + 0.01f;
            e0 = u; e1 = v; eA = a2; eB = b2; eC = c2; eOp = op;
            eR = cr; eG = cg; eBc = cb;
        }
    }

    if (lane < 12) {
        float val;
        switch (lane) {
            case 0:  val = e0;  break;
            case 1:  val = e1;  break;
            case 2:  val = rx;  break;
            case 3:  val = ry;  break;
            case 4:  val = eA;  break;
            case 5:  val = eB;  break;
            case 6:  val = eC;  break;
            case 7:  val = eOp; break;
            case 8:  val = eR;  break;
            case 9:  val = eG;  break;
            case 10: val = eBc; break;
            default: val = 0.f; break;
        }
        sorted[12*(size_t)cntk + lane] = val;
    }
}

// ---------------------------------------------------------------------------
// Render: tiles*NLAYER blocks x 512 threads. Each wave owns one 8x8 pixel
// tile (lane -> (lane&7, lane>>3)) and one depth segment of 64 gaussians.
// Per gaussian: wave-uniform bbox test (all lanes share the record) ->
// s_cbranch_execz skips the 17-op body for ~83% of pairs; exact because
// outside the bbox alpha < 1/255 is clamped to 0 anyway. Next record header
// is prefetched across the branch. In-block LDS fold of 8 segments; the
// last of the 4 layer-blocks (per-tile atomic counter) folds the 4 layer
// partials and writes the final image (combine kernel fused away).
// ---------------------------------------------------------------------------
__global__ __launch_bounds__(512, 8) void render_main_kernel(
        const float* __restrict__ sorted,
        float4* __restrict__ parts,
        int* __restrict__ cnt,
        float* __restrict__ out,
        int N, int P) {
    __shared__ float4 part[LSEG][64];
    int tid  = threadIdx.x;
    int lane = tid & 63;
    int w    = __builtin_amdgcn_readfirstlane(tid >> 6);
    int L    = blockIdx.x & (NLAYER - 1);
    int tile = blockIdx.x >> 2;
    int tiles = P >> 6;

    // width = 128 fixed by problem setup -> 16x16 grid of 8x8 tiles
    int tx = tile & 15, ty = tile >> 4;
    float x0 = (float)(tx * 8) + 0.5f;
    float y0 = (float)(ty * 8) + 0.5f;
    float x1 = x0 + 7.f, y1 = y0 + 7.f;
    float px = x0 + (float)(lane & 7);
    float py = y0 + (float)(lane >> 3);

    int chunk = (N + SEGS - 1) / SEGS;
    int s  = L * LSEG + w;
    int g0 = s * chunk;
    int g1 = min(g0 + chunk, N);

    const float4* rec = (const float4*)sorted + 3*(size_t)g0;

    float accr = 0.f, accg = 0.f, accb = 0.f, T = 1.f;
    float4 r0 = rec[0];                      // {u, v, rx, ry}
    for (int g = g0; g < g1; ++g, rec += 3) {
        float4 r0n = rec[3];                 // prefetch next header (dummy at N)
        bool hit = (r0.y + r0.w >= y0) && (r0.y - r0.w <= y1) &&
                   (r0.x + r0.z >= x0) && (r0.x - r0.z <= x1);
        if (hit) {
            float4 r1 = rec[1];              // A2', B', C2', op
            float4 r2 = rec[2];              // cr, cg, cb, 0
            float dx = px - r0.x, dy = py - r0.y;
            float t2 = fmaf(r1.x, dx, r1.y * dy);     // A2'*dx + B'*dy
            float m  = dx * t2;
            float arg = fmaf(-r1.z, dy*dy, -m);       // -(sigma*log2e)
            float al = r1.w * __builtin_amdgcn_exp2f(arg);
            al = fminf(al, ALPHA_MAX);
            al = (al >= ALPHA_MIN) ? al : 0.f;
            float wgt = T * al;
            accr = fmaf(wgt, r2.x, accr);
            accg = fmaf(wgt, r2.y, accg);
            accb = fmaf(wgt, r2.z, accb);
            T = fmaf(-al, T, T);
        }
        r0 = r0n;
    }
    part[w][lane] = make_float4(accr, accg, accb, T);
    __syncthreads();

    if (tid < 64) {
        float R = 0.f, G = 0.f, Bc = 0.f, Tr = 1.f;
        #pragma unroll
        for (int ss = 0; ss < LSEG; ++ss) {
            float4 q = part[ss][tid];
            R  = fmaf(Tr, q.x, R);
            G  = fmaf(Tr, q.y, G);
            Bc = fmaf(Tr, q.z, Bc);
            Tr *= q.w;
        }
        parts[((size_t)L * tiles + tile) * 64 + tid] = make_float4(R, G, Bc, Tr);
        __threadfence();                     // release partial before signaling
        int old = 0;
        if (tid == 0) old = atomicAdd(&cnt[tile], 1);
        old = __shfl(old, 0, 64);
        if (old == NLAYER - 1) {             // last layer-block: fold & write
            __threadfence();                 // acquire other layers' partials
            float R2 = 0.f, G2 = 0.f, B2 = 0.f, Tr2 = 1.f;
            #pragma unroll
            for (int l = 0; l < NLAYER; ++l) {
                float4 q = parts[((size_t)l * tiles + tile) * 64 + tid];
                R2 = fmaf(Tr2, q.x, R2);
                G2 = fmaf(Tr2, q.y, G2);
                B2 = fmaf(Tr2, q.z, B2);
                Tr2 *= q.w;
            }
            int p = (ty * 8 + (tid >> 3)) * 128 + tx * 8 + (tid & 7);
            out[3*(size_t)p+0] = R2;
            out[3*(size_t)p+1] = G2;
            out[3*(size_t)p+2] = B2;
        }
    }
}

extern "C" void kernel_launch(void* const* d_in, const int* in_sizes, int n_in,
                              void* d_out, int out_size, void* d_ws, size_t ws_size,
                              hipStream_t stream) {
    const float* means     = (const float*)d_in[0];
    const float* quats     = (const float*)d_in[1];
    const float* scales    = (const float*)d_in[2];
    const float* opacities = (const float*)d_in[3];
    const float* sh        = (const float*)d_in[4];
    const float* vm        = (const float*)d_in[5];
    const float* K         = (const float*)d_in[6];

    int N = in_sizes[0] / 3;   // gaussians
    int P = out_size / 3;      // pixels
    int tiles = P / 64;

    float*  sorted = (float*)d_ws;                                   // (N+1)*12 floats
    float4* parts  = (float4*)((float*)d_ws + (size_t)(N+1) * 12);   // NLAYER*P float4
    int*    cnt    = (int*)(parts + (size_t)NLAYER * P);             // tiles ints

    prep_rank_kernel<<<(N + 3) / 4, 256, 0, stream>>>(
        means, quats, scales, opacities, sh, vm, K, sorted, cnt, N, tiles);
    render_main_kernel<<<tiles * NLAYER, 512, 0, stream>>>(
        sorted, parts, cnt, (float*)d_out, N, P);
}

// Round 2
// 92.062 us; speedup vs baseline: 1.3769x; 1.3769x over previous
//
#include <hip/hip_runtime.h>
#include <math.h>

#define SH_C0     0.28209479177387814f
#define EPS2D     0.3f
#define NEARZ     0.01f
#define ALPHA_MIN (1.0f/255.0f)
#define ALPHA_MAX 0.999f
#define LOG2E     1.4426950408889634f

#define LSEG    8                  // waves per render block
#define NLAYER  8                  // depth layer-blocks per tile
#define SEGS_R  (NLAYER * LSEG)    // 64 list segments per tile
#define GSTRIDE 2052               // per-tile list capacity (N<=2048 + 4 pad)

// ---------------------------------------------------------------------------
// Pass 1: fused preprocess + stable-rank + scatter. One 64-lane wave per
// gaussian. Record (12 floats, 48B, float4-aligned):
//   rec[0] = {u, v, rx, ry}      bbox half-widths of the alpha>=1/255 ellipse
//   rec[1] = {A2', B', C2', op}  sigma in log2 domain (0.5*conA*log2e, ...)
//   rec[2] = {cr, cg, cb, 0}
// Invisible gaussians (z<=NEAR, det<=0, op*255<=1): all-zero record -> culled
// by every tile's bbox test (tile x0,y0 >= 0.5 > 0) -> contributes exactly 0,
// same as the reference clamp. Rank key = (zc>NEAR ? zc : +inf), stable ties
// == reference argsort. Block 0 zeroes dummy record N (list-pad target:
// al = 0 * exp2(0) = 0 -> exact no-op contribution).
// ---------------------------------------------------------------------------
__global__ __launch_bounds__(256) void prep_rank_kernel(
        const float* __restrict__ means,
        const float* __restrict__ quats,
        const float* __restrict__ scales,
        const float* __restrict__ opacities,
        const float* __restrict__ sh,
        const float* __restrict__ vm,
        const float* __restrict__ K,
        float* __restrict__ sorted,
        int N) {
    if (blockIdx.x == 0 && threadIdx.x < 12)
        sorted[12*(size_t)N + threadIdx.x] = 0.f;

    int wave = blockIdx.x * 4 + (threadIdx.x >> 6);
    int lane = threadIdx.x & 63;
    if (wave >= N) return;
    int i = wave;

    float r00=vm[0], r01=vm[1], r02=vm[2],  t0=vm[3];
    float r10=vm[4], r11=vm[5], r12=vm[6],  t1=vm[7];
    float r20=vm[8], r21=vm[9], r22=vm[10], t2=vm[11];

    // --- stable rank: count keys strictly smaller (ties: j < i) ---
    float mx = means[3*i+0], my = means[3*i+1], mz = means[3*i+2];
    float zci = r20*mx + r21*my + r22*mz + t2;
    float keyi = (zci > NEARZ) ? zci : INFINITY;
    int cntk = 0;
    for (int j = lane; j < N; j += 64) {
        float ax = means[3*j+0], ay = means[3*j+1], az = means[3*j+2];
        float zcj = r20*ax + r21*ay + r22*az + t2;
        float keyj = (zcj > NEARZ) ? zcj : INFINITY;
        cntk += (keyj < keyi) || (keyj == keyi && j < i);
    }
    #pragma unroll
    for (int off = 32; off > 0; off >>= 1)
        cntk += __shfl_xor(cntk, off, 64);

    // --- preprocess (redundant across lanes; uniform loads) ---
    float qw = quats[4*i+0], qx = quats[4*i+1], qy = quats[4*i+2], qz = quats[4*i+3];
    float rqn = rsqrtf(qw*qw + qx*qx + qy*qy + qz*qz);
    qw *= rqn; qx *= rqn; qy *= rqn; qz *= rqn;

    float R00 = 1.f - 2.f*(qy*qy + qz*qz);
    float R01 = 2.f*(qx*qy - qw*qz);
    float R02 = 2.f*(qx*qz + qw*qy);
    float R10 = 2.f*(qx*qy + qw*qz);
    float R11 = 1.f - 2.f*(qx*qx + qz*qz);
    float R12 = 2.f*(qy*qz - qw*qx);
    float R20 = 2.f*(qx*qz - qw*qy);
    float R21 = 2.f*(qy*qz + qw*qx);
    float R22 = 1.f - 2.f*(qx*qx + qy*qy);

    float s0 = fminf(expf(scales[3*i+0]), 10.f);
    float s1 = fminf(expf(scales[3*i+1]), 10.f);
    float s2 = fminf(expf(scales[3*i+2]), 10.f);

    float M00=R00*s0, M01=R01*s1, M02=R02*s2;
    float M10=R10*s0, M11=R11*s1, M12=R12*s2;
    float M20=R20*s0, M21=R21*s1, M22=R22*s2;

    float c00 = M00*M00 + M01*M01 + M02*M02;
    float c01 = M00*M10 + M01*M11 + M02*M12;
    float c02 = M00*M20 + M01*M21 + M02*M22;
    float c11 = M10*M10 + M11*M11 + M12*M12;
    float c12 = M10*M20 + M11*M21 + M12*M22;
    float c22 = M20*M20 + M21*M21 + M22*M22;

    float xc = r00*mx + r01*my + r02*mz + t0;
    float yc = r10*mx + r11*my + r12*mz + t1;
    float zc = zci;

    float T00 = r00*c00 + r01*c01 + r02*c02;
    float T01 = r00*c01 + r01*c11 + r02*c12;
    float T02 = r00*c02 + r01*c12 + r02*c22;
    float T10 = r10*c00 + r11*c01 + r12*c02;
    float T11 = r10*c01 + r11*c11 + r12*c12;
    float T12 = r10*c02 + r11*c12 + r12*c22;
    float T20 = r20*c00 + r21*c01 + r22*c02;
    float T21 = r20*c01 + r21*c11 + r22*c12;
    float T22 = r20*c02 + r21*c12 + r22*c22;
    float V00 = T00*r00 + T01*r01 + T02*r02;
    float V01 = T00*r10 + T01*r11 + T02*r12;
    float V02 = T00*r20 + T01*r21 + T02*r22;
    float V11 = T10*r10 + T11*r11 + T12*r12;
    float V12 = T10*r20 + T11*r21 + T12*r22;
    float V22 = T20*r20 + T21*r21 + T22*r22;

    float fx = K[0], cx = K[2], fy = K[4], cy = K[5];

    bool valid = zc > NEARZ;
    float zs = valid ? zc : 1.0f;
    float rz = 1.0f / zs;
    float u = fx*xc*rz + cx;
    float v = fy*yc*rz + cy;
    float J00 = fx*rz;
    float J02 = -fx*xc*rz*rz;
    float J11 = fy*rz;
    float J12 = -fy*yc*rz*rz;

    float a = J00*J00*V00 + 2.f*J00*J02*V02 + J02*J02*V22 + EPS2D;
    float b = J00*(J11*V01 + J12*V02) + J02*(J11*V12 + J12*V22);
    float c = J11*J11*V11 + 2.f*J11*J12*V12 + J12*J12*V22 + EPS2D;
    float det = a*c - b*b;
    valid = valid && (det > 0.f);
    float det_s = valid ? det : 1.0f;
    float conA =  c / det_s;
    float conB = -b / det_s;
    float conC =  a / det_s;

    float op  = 1.0f / (1.0f + expf(-opacities[i]));
    float cr = fmaxf(sh[3*i+0]*SH_C0 + 0.5f, 0.f);
    float cg = fmaxf(sh[3*i+1]*SH_C0 + 0.5f, 0.f);
    float cb = fmaxf(sh[3*i+2]*SH_C0 + 0.5f, 0.f);

    // bbox of {alpha >= 1/255}: rx = sqrt(qmax*C2'/det2), ry = sqrt(qmax*A2'/det2)
    float e0=0,e1=0,eA=0,eB=0,eC=0,eOp=0,eR=0,eG=0,eBc=0,rx=0,ry=0;
    if (valid) {
        float qmax = log2f(op * 255.f);
        if (qmax > 0.f) {
            float a2 = 0.5f*conA*LOG2E;
            float b2 = conB*LOG2E;
            float c2 = 0.5f*conC*LOG2E;
            float det2 = a2*c2 - 0.25f*b2*b2;
            float inv = qmax / det2;
            rx = sqrtf(c2 * inv) * 1.0001f + 0.01f;
            ry = sqrtf(a2 * inv) * 1.0001f + 0.01f;
            e0 = u; e1 = v; eA = a2; eB = b2; eC = c2; eOp = op;
            eR = cr; eG = cg; eBc = cb;
        }
    }

    if (lane < 12) {
        float val;
        switch (lane) {
            case 0:  val = e0;  break;
            case 1:  val = e1;  break;
            case 2:  val = rx;  break;
            case 3:  val = ry;  break;
            case 4:  val = eA;  break;
            case 5:  val = eB;  break;
            case 6:  val = eC;  break;
            case 7:  val = eOp; break;
            case 8:  val = eR;  break;
            case 9:  val = eG;  break;
            case 10: val = eBc; break;
            default: val = 0.f; break;
        }
        sorted[12*(size_t)cntk + lane] = val;
    }
}

// ---------------------------------------------------------------------------
// Pass 2: per-tile cull + ordered compaction. One 512-thread block per 8x8
// tile; wave w tests gaussians [w*ceil(N/8), ...) in depth order, ballot-
// compacts hit indices into LDS, then an LDS scan concatenates the 8 wave
// lists into the tile's global list (depth order preserved -> compositing
// is bit-compatible: culled gaussians contributed exactly 0). The list is
// padded with 4 dummy indices (=N, zero record) so render needs no tail
// branches. Assumes N <= 2048 (problem-fixed).
// ---------------------------------------------------------------------------
__global__ __launch_bounds__(512) void cull_compact_kernel(
        const float* __restrict__ sorted,
        int* __restrict__ glist,
        int* __restrict__ lens,
        int N) {
    __shared__ int lbuf[8][256];
    __shared__ int lcnt[8];
    __shared__ int lbase[9];
    int tid  = threadIdx.x;
    int lane = tid & 63;
    int w    = tid >> 6;
    int t    = blockIdx.x;
    int tx = t & 15, ty = t >> 4;        // width=128 -> 16x16 tiles
    float x0 = (float)(tx * 8) + 0.5f, x1 = x0 + 7.f;
    float y0 = (float)(ty * 8) + 0.5f, y1 = y0 + 7.f;

    int chunkW = (N + 7) / 8;            // 256 for N=2048
    int gs = w * chunkW;
    int ge = min(gs + chunkW, N);

    int cnt = 0;
    for (int base = gs; base < ge; base += 64) {
        int gi = base + lane;
        int g  = min(gi, N - 1);
        const float4 h = *(const float4*)(sorted + 12*(size_t)g);  // u,v,rx,ry
        bool hit = (gi < ge) &&
                   (h.y + h.w >= y0) && (h.y - h.w <= y1) &&
                   (h.x + h.z >= x0) && (h.x - h.z <= x1);
        unsigned long long m = __ballot(hit);
        int pos = cnt + __popcll(m & ((1ull << lane) - 1ull));
        if (hit) lbuf[w][pos] = gi;
        cnt += (int)__popcll(m);
    }
    if (lane == 0) lcnt[w] = cnt;
    __syncthreads();
    if (tid == 0) {
        int acc = 0;
        #pragma unroll
        for (int i = 0; i < 8; ++i) { lbase[i] = acc; acc += lcnt[i]; }
        lbase[8] = acc;
    }
    __syncthreads();
    int b = lbase[w];
    int* dst = glist + (size_t)t * GSTRIDE;
    for (int j = lane; j < cnt; j += 64) dst[b + j] = lbuf[w][j];
    int total = lbase[8];
    if (tid < 4)  dst[total + tid] = N;   // pad -> dummy zero record
    if (tid == 0) lens[t] = total;
}

// ---------------------------------------------------------------------------
// Pass 3: render. tiles*NLAYER blocks x 512 threads. Wave = one 8x8 tile x
// one depth segment of the tile's COMPACT list (branch-free, no fences).
// chunk rounded to x4 so int4 index loads stay aligned; overruns land on
// the padded dummy index. In-block LDS fold of 8 waves -> one (C,T) partial
// per pixel per layer.
// ---------------------------------------------------------------------------
__global__ __launch_bounds__(512, 4) void render_main_kernel(
        const float* __restrict__ sorted,
        const int* __restrict__ glist,
        const int* __restrict__ lens,
        float4* __restrict__ parts,
        int N, int P) {
    __shared__ float4 part[LSEG][64];
    int tid  = threadIdx.x;
    int lane = tid & 63;
    int w    = __builtin_amdgcn_readfirstlane(tid >> 6);
    int L    = blockIdx.x & (NLAYER - 1);
    int tile = blockIdx.x >> 3;          // log2(NLAYER)
    int tx = tile & 15, ty = tile >> 4;
    float px = (float)(tx * 8 + (lane & 7)) + 0.5f;
    float py = (float)(ty * 8 + (lane >> 3)) + 0.5f;

    int len   = lens[tile];
    int chunk = (((len + SEGS_R - 1) / SEGS_R) + 3) & ~3;
    int s     = L * LSEG + w;
    int k0    = s * chunk;
    int lenp  = (len + 3) & ~3;
    int k1    = min(k0 + chunk, lenp);
    const int* lst = glist + (size_t)tile * GSTRIDE;

    float accr = 0.f, accg = 0.f, accb = 0.f, T = 1.f;
    for (int k = k0; k < k1; k += 4) {
        int4 gi = *(const int4*)(lst + k);
        int idx0 = gi.x, idx1 = gi.y, idx2 = gi.z, idx3 = gi.w;
        #pragma unroll
        for (int j = 0; j < 4; ++j) {
            int g = (j == 0) ? idx0 : (j == 1) ? idx1 : (j == 2) ? idx2 : idx3;
            const float4* rec = (const float4*)sorted + 3*(size_t)g;
            float4 r0 = rec[0];          // u, v, rx, ry
            float4 r1 = rec[1];          // A2', B', C2', op
            float4 r2 = rec[2];          // cr, cg, cb, 0
            float dx = px - r0.x, dy = py - r0.y;
            float t2 = fmaf(r1.x, dx, r1.y * dy);    // A2'*dx + B'*dy
            float m  = dx * t2;
            float arg = fmaf(-r1.z, dy*dy, -m);      // -(sigma*log2e)
            float al = r1.w * __builtin_amdgcn_exp2f(arg);
            al = fminf(al, ALPHA_MAX);
            al = (al >= ALPHA_MIN) ? al : 0.f;
            float wgt = T * al;
            accr = fmaf(wgt, r2.x, accr);
            accg = fmaf(wgt, r2.y, accg);
            accb = fmaf(wgt, r2.z, accb);
            T = fmaf(-al, T, T);
        }
    }
    part[w][lane] = make_float4(accr, accg, accb, T);
    __syncthreads();

    if (tid < 64) {
        float R = 0.f, G = 0.f, Bc = 0.f, Tr = 1.f;
        #pragma unroll
        for (int ss = 0; ss < LSEG; ++ss) {
            float4 q = part[ss][tid];
            R  = fmaf(Tr, q.x, R);
            G  = fmaf(Tr, q.y, G);
            Bc = fmaf(Tr, q.z, Bc);
            Tr *= q.w;
        }
        int p = (ty * 8 + (tid >> 3)) * 128 + tx * 8 + (tid & 7);
        parts[(size_t)L * P + p] = make_float4(R, G, Bc, Tr);
    }
}

// Fold the 8 layers: C = C0 + T0*(C1 + T1*(... C7)).
__global__ __launch_bounds__(256) void combine_kernel(
        const float4* __restrict__ parts,
        float* __restrict__ out, int P) {
    int p = blockIdx.x * 256 + threadIdx.x;
    if (p >= P) return;
    float R = 0.f, G = 0.f, B = 0.f, Tr = 1.f;
    #pragma unroll
    for (int l = 0; l < NLAYER; ++l) {
        float4 q = parts[(size_t)l * P + p];
        R  = fmaf(Tr, q.x, R);
        G  = fmaf(Tr, q.y, G);
        B  = fmaf(Tr, q.z, B);
        Tr *= q.w;
    }
    out[3*(size_t)p+0] = R;
    out[3*(size_t)p+1] = G;
    out[3*(size_t)p+2] = B;
}

extern "C" void kernel_launch(void* const* d_in, const int* in_sizes, int n_in,
                              void* d_out, int out_size, void* d_ws, size_t ws_size,
                              hipStream_t stream) {
    const float* means     = (const float*)d_in[0];
    const float* quats     = (const float*)d_in[1];
    const float* scales    = (const float*)d_in[2];
    const float* opacities = (const float*)d_in[3];
    const float* sh        = (const float*)d_in[4];
    const float* vm        = (const float*)d_in[5];
    const float* K         = (const float*)d_in[6];

    int N = in_sizes[0] / 3;   // gaussians (2048)
    int P = out_size / 3;      // pixels (16384)
    int tiles = P / 64;        // 256 (8x8 tiles on 128x128)

    float*  sorted = (float*)d_ws;                              // (N+1)*12 floats
    int*    glist  = (int*)(sorted + (size_t)(N + 1) * 12);     // tiles*GSTRIDE
    int*    lens   = glist + (size_t)tiles * GSTRIDE;           // tiles
    float4* parts  = (float4*)(lens + tiles);                   // NLAYER*P

    prep_rank_kernel<<<(N + 3) / 4, 256, 0, stream>>>(
        means, quats, scales, opacities, sh, vm, K, sorted, N);
    cull_compact_kernel<<<tiles, 512, 0, stream>>>(
        sorted, glist, lens, N);
    render_main_kernel<<<tiles * NLAYER, 512, 0, stream>>>(
        sorted, glist, lens, parts, N, P);
    combine_kernel<<<(P + 255) / 256, 256, 0, stream>>>(
        parts, (float*)d_out, P);
}

// Round 3
// 87.693 us; speedup vs baseline: 1.4455x; 1.0498x over previous
//
#include <hip/hip_runtime.h>
#include <math.h>

#define SH_C0     0.28209479177387814f
#define EPS2D     0.3f
#define NEARZ     0.01f
#define ALPHA_MIN (1.0f/255.0f)
#define ALPHA_MAX 0.999f
#define LOG2E     1.4426950408889634f

#define NLAYER  4    // depth layer-blocks per tile
#define LSEG    8    // waves per render block
#define WSTRIDE 72   // per-wave LDS list region: 64 hits + pad, 288B (16B-mult)
#define MAXN    2048 // problem-fixed N (kbuf sizing)

// ---------------------------------------------------------------------------
// Pass 1: fused preprocess + stable-rank + scatter. 512-thread blocks; the
// block first computes ALL N depth keys into LDS (means read once per block,
// 6 MB total vs 48 MB for the per-wave global re-read), then wave w ranks
// gaussian i = blockIdx*8 + w against the LDS keys. Validity and key both
// derive from the same kbuf value -> rank is a strict total order.
// Outputs per gaussian, scattered to depth-rank position:
//   sorted[12r..] = {u,v,rx,ry | A2',B',C2',op | cr,cg,cb,0}  (48B record)
//   hdr[r]        = {u,v,rx,ry}                               (dense cull array)
// Invisible gaussians (inf key, det<=0, op*255<=1): all-zero record+hdr ->
// rx=ry=0 fails every tile's bbox test (tile x0 >= 0.5) -> exact 0 contrib,
// same as the reference's alpha clamp. Dummy record at index N = zeros
// (list-pad target: al = 0*exp2(0) = 0).
// ---------------------------------------------------------------------------
__global__ __launch_bounds__(512) void prep_rank_kernel(
        const float* __restrict__ means,
        const float* __restrict__ quats,
        const float* __restrict__ scales,
        const float* __restrict__ opacities,
        const float* __restrict__ sh,
        const float* __restrict__ vm,
        const float* __restrict__ K,
        float* __restrict__ sorted,
        float4* __restrict__ hdr,
        int N) {
    __shared__ float kbuf[MAXN];
    int tid = threadIdx.x;

    float r00=vm[0], r01=vm[1], r02=vm[2],  t0=vm[3];
    float r10=vm[4], r11=vm[5], r12=vm[6],  t1=vm[7];
    float r20=vm[8], r21=vm[9], r22=vm[10], t2=vm[11];

    for (int j = tid; j < N; j += 512) {
        float zc = r20*means[3*j+0] + r21*means[3*j+1] + r22*means[3*j+2] + t2;
        kbuf[j] = (zc > NEARZ) ? zc : INFINITY;
    }
    __syncthreads();

    if (blockIdx.x == 0 && tid < 12)
        sorted[12*(size_t)N + tid] = 0.f;

    int lane = tid & 63;
    int w    = tid >> 6;
    int i    = blockIdx.x * 8 + w;
    if (i >= N) return;               // no further __syncthreads below

    // --- stable rank from LDS keys (ties: j < i) ---
    float keyi = kbuf[i];
    int cntk = 0;
    for (int j = lane; j < N; j += 64) {
        float kj = kbuf[j];
        cntk += (kj < keyi) || (kj == keyi && j < i);
    }
    #pragma unroll
    for (int off = 32; off > 0; off >>= 1)
        cntk += __shfl_xor(cntk, off, 64);

    // --- preprocess (redundant across lanes; uniform loads) ---
    float mx = means[3*i+0], my = means[3*i+1], mz = means[3*i+2];
    float qw = quats[4*i+0], qx = quats[4*i+1], qy = quats[4*i+2], qz = quats[4*i+3];
    float rqn = rsqrtf(qw*qw + qx*qx + qy*qy + qz*qz);
    qw *= rqn; qx *= rqn; qy *= rqn; qz *= rqn;

    float R00 = 1.f - 2.f*(qy*qy + qz*qz);
    float R01 = 2.f*(qx*qy - qw*qz);
    float R02 = 2.f*(qx*qz + qw*qy);
    float R10 = 2.f*(qx*qy + qw*qz);
    float R11 = 1.f - 2.f*(qx*qx + qz*qz);
    float R12 = 2.f*(qy*qz - qw*qx);
    float R20 = 2.f*(qx*qz - qw*qy);
    float R21 = 2.f*(qy*qz + qw*qx);
    float R22 = 1.f - 2.f*(qx*qx + qy*qy);

    float s0 = fminf(expf(scales[3*i+0]), 10.f);
    float s1 = fminf(expf(scales[3*i+1]), 10.f);
    float s2 = fminf(expf(scales[3*i+2]), 10.f);

    float M00=R00*s0, M01=R01*s1, M02=R02*s2;
    float M10=R10*s0, M11=R11*s1, M12=R12*s2;
    float M20=R20*s0, M21=R21*s1, M22=R22*s2;

    float c00 = M00*M00 + M01*M01 + M02*M02;
    float c01 = M00*M10 + M01*M11 + M02*M12;
    float c02 = M00*M20 + M01*M21 + M02*M22;
    float c11 = M10*M10 + M11*M11 + M12*M12;
    float c12 = M10*M20 + M11*M21 + M12*M22;
    float c22 = M20*M20 + M21*M21 + M22*M22;

    float xc = r00*mx + r01*my + r02*mz + t0;
    float yc = r10*mx + r11*my + r12*mz + t1;

    float T00 = r00*c00 + r01*c01 + r02*c02;
    float T01 = r00*c01 + r01*c11 + r02*c12;
    float T02 = r00*c02 + r01*c12 + r02*c22;
    float T10 = r10*c00 + r11*c01 + r12*c02;
    float T11 = r10*c01 + r11*c11 + r12*c12;
    float T12 = r10*c02 + r11*c12 + r12*c22;
    float T20 = r20*c00 + r21*c01 + r22*c02;
    float T21 = r20*c01 + r21*c11 + r22*c12;
    float T22 = r20*c02 + r21*c12 + r22*c22;
    float V00 = T00*r00 + T01*r01 + T02*r02;
    float V01 = T00*r10 + T01*r11 + T02*r12;
    float V02 = T00*r20 + T01*r21 + T02*r22;
    float V11 = T10*r10 + T11*r11 + T12*r12;
    float V12 = T10*r20 + T11*r21 + T12*r22;
    float V22 = T20*r20 + T21*r21 + T22*r22;

    float fx = K[0], cx = K[2], fy = K[4], cy = K[5];

    bool valid = keyi < INFINITY;     // zc > NEARZ, same value as rank key
    float zc = valid ? keyi : 1.0f;
    float rz = 1.0f / zc;
    float u = fx*xc*rz + cx;
    float v = fy*yc*rz + cy;
    float J00 = fx*rz;
    float J02 = -fx*xc*rz*rz;
    float J11 = fy*rz;
    float J12 = -fy*yc*rz*rz;

    float a = J00*J00*V00 + 2.f*J00*J02*V02 + J02*J02*V22 + EPS2D;
    float b = J00*(J11*V01 + J12*V02) + J02*(J11*V12 + J12*V22);
    float c = J11*J11*V11 + 2.f*J11*J12*V12 + J12*J12*V22 + EPS2D;
    float det = a*c - b*b;
    valid = valid && (det > 0.f);
    float det_s = valid ? det : 1.0f;
    float conA =  c / det_s;
    float conB = -b / det_s;
    float conC =  a / det_s;

    float op  = 1.0f / (1.0f + expf(-opacities[i]));
    float cr = fmaxf(sh[3*i+0]*SH_C0 + 0.5f, 0.f);
    float cg = fmaxf(sh[3*i+1]*SH_C0 + 0.5f, 0.f);
    float cb = fmaxf(sh[3*i+2]*SH_C0 + 0.5f, 0.f);

    // bbox of {alpha >= 1/255}: rx = sqrt(qmax*C2'/det2), ry = sqrt(qmax*A2'/det2)
    float e0=0,e1=0,eA=0,eB=0,eC=0,eOp=0,eR=0,eG=0,eBc=0,rx=0,ry=0;
    if (valid) {
        float qmax = log2f(op * 255.f);
        if (qmax > 0.f) {
            float a2 = 0.5f*conA*LOG2E;
            float b2 = conB*LOG2E;
            float c2 = 0.5f*conC*LOG2E;
            float det2 = a2*c2 - 0.25f*b2*b2;
            float inv = qmax / det2;
            rx = sqrtf(c2 * inv) * 1.0001f + 0.01f;
            ry = sqrtf(a2 * inv) * 1.0001f + 0.01f;
            e0 = u; e1 = v; eA = a2; eB = b2; eC = c2; eOp = op;
            eR = cr; eG = cg; eBc = cb;
        }
    }

    if (lane < 12) {
        float val;
        switch (lane) {
            case 0:  val = e0;  break;
            case 1:  val = e1;  break;
            case 2:  val = rx;  break;
            case 3:  val = ry;  break;
            case 4:  val = eA;  break;
            case 5:  val = eB;  break;
            case 6:  val = eC;  break;
            case 7:  val = eOp; break;
            case 8:  val = eR;  break;
            case 9:  val = eG;  break;
            case 10: val = eBc; break;
            default: val = 0.f; break;
        }
        sorted[12*(size_t)cntk + lane] = val;
    }
    if (lane == 0)
        hdr[cntk] = make_float4(e0, e1, rx, ry);
}

// ---------------------------------------------------------------------------
// Pass 2: fused cull + render. tiles*NLAYER blocks x 512 threads. Block
// (tile, L) covers depth range [L*chunkB, (L+1)*chunkB); wave w owns the
// CONTIGUOUS depth slice [gs, gs+cw) of that range, so per-wave compacted
// lists are depth-ordered and the in-order LDS fold across waves 0..7
// reconstructs the exact composite order -- no cross-wave scan needed.
// Cull: one ballot pass over the dense 16B hdr array into a private LDS
// index list (pad to x4 with dummy index N). Render: branch-free int4 LDS
// index loads + 3x float4 record loads, same body as the verified round-2
// kernel. No fences, no atomics.
// ---------------------------------------------------------------------------
__global__ __launch_bounds__(512, 8) void render_kernel(
        const float* __restrict__ sorted,
        const float4* __restrict__ hdr,
        float4* __restrict__ parts,
        int N, int P) {
    __shared__ __align__(16) int lbuf[LSEG * WSTRIDE];
    __shared__ float4 part[LSEG][64];
    int tid  = threadIdx.x;
    int lane = tid & 63;
    int w    = __builtin_amdgcn_readfirstlane(tid >> 6);
    int L    = blockIdx.x & (NLAYER - 1);
    int tile = blockIdx.x >> 2;          // log2(NLAYER)
    int tx = tile & 15, ty = tile >> 4;  // width=128 -> 16x16 tiles of 8x8
    float x0 = (float)(tx * 8) + 0.5f, x1 = x0 + 7.f;
    float y0 = (float)(ty * 8) + 0.5f, y1 = y0 + 7.f;
    float px = x0 + (float)(lane & 7);
    float py = y0 + (float)(lane >> 3);

    int chunkB = (N + NLAYER - 1) / NLAYER;   // 512 for N=2048
    int cw     = (chunkB + LSEG - 1) / LSEG;  // 64
    int lend   = min((L + 1) * chunkB, N);
    int gs     = L * chunkB + w * cw;
    int ge     = min(gs + cw, lend);
    int* lw    = lbuf + w * WSTRIDE;

    // --- cull this wave's depth slice into its private LDS list ---
    int cnt = 0;
    for (int base = gs; base < ge; base += 64) {
        int gi = base + lane;
        float4 h = hdr[min(gi, N - 1)];       // {u, v, rx, ry}
        bool hit = (gi < ge) &&
                   (h.y + h.w >= y0) && (h.y - h.w <= y1) &&
                   (h.x + h.z >= x0) && (h.x - h.z <= x1);
        unsigned long long m = __ballot(hit);
        int pos = cnt + (int)__popcll(m & ((1ull << lane) - 1ull));
        if (hit) lw[pos] = gi;
        cnt += (int)__popcll(m);
    }
    int cpad = (cnt + 3) & ~3;
    if (lane < cpad - cnt) lw[cnt + lane] = N;   // pad -> dummy zero record

    // --- render the compact list (branch-free) ---
    float accr = 0.f, accg = 0.f, accb = 0.f, T = 1.f;
    for (int k = 0; k < cpad; k += 4) {
        int4 gi4 = *(const int4*)(lw + k);
        #pragma unroll
        for (int j = 0; j < 4; ++j) {
            int g = (j == 0) ? gi4.x : (j == 1) ? gi4.y : (j == 2) ? gi4.z : gi4.w;
            const float4* rec = (const float4*)sorted + 3*(size_t)g;
            float4 r0 = rec[0];          // u, v, rx, ry
            float4 r1 = rec[1];          // A2', B', C2', op
            float4 r2 = rec[2];          // cr, cg, cb, 0
            float dx = px - r0.x, dy = py - r0.y;
            float t2 = fmaf(r1.x, dx, r1.y * dy);    // A2'*dx + B'*dy
            float m  = dx * t2;
            float arg = fmaf(-r1.z, dy*dy, -m);      // -(sigma*log2e)
            float al = r1.w * __builtin_amdgcn_exp2f(arg);
            al = fminf(al, ALPHA_MAX);
            al = (al >= ALPHA_MIN) ? al : 0.f;
            float wgt = T * al;
            accr = fmaf(wgt, r2.x, accr);
            accg = fmaf(wgt, r2.y, accg);
            accb = fmaf(wgt, r2.z, accb);
            T = fmaf(-al, T, T);
        }
    }
    part[w][lane] = make_float4(accr, accg, accb, T);
    __syncthreads();

    // --- fold the 8 depth-ordered wave partials; write layer partial ---
    if (tid < 64) {
        float R = 0.f, G = 0.f, Bc = 0.f, Tr = 1.f;
        #pragma unroll
        for (int ss = 0; ss < LSEG; ++ss) {
            float4 q = part[ss][tid];
            R  = fmaf(Tr, q.x, R);
            G  = fmaf(Tr, q.y, G);
            Bc = fmaf(Tr, q.z, Bc);
            Tr *= q.w;
        }
        int p = (ty * 8 + (tid >> 3)) * 128 + tx * 8 + (tid & 7);
        parts[(size_t)L * P + p] = make_float4(R, G, Bc, Tr);
    }
}

// Fold the 4 layers: C = C0 + T0*(C1 + T1*(C2 + T2*C3)).
__global__ __launch_bounds__(256) void combine_kernel(
        const float4* __restrict__ parts,
        float* __restrict__ out, int P) {
    int p = blockIdx.x * 256 + threadIdx.x;
    if (p >= P) return;
    float R = 0.f, G = 0.f, B = 0.f, Tr = 1.f;
    #pragma unroll
    for (int l = 0; l < NLAYER; ++l) {
        float4 q = parts[(size_t)l * P + p];
        R  = fmaf(Tr, q.x, R);
        G  = fmaf(Tr, q.y, G);
        B  = fmaf(Tr, q.z, B);
        Tr *= q.w;
    }
    out[3*(size_t)p+0] = R;
    out[3*(size_t)p+1] = G;
    out[3*(size_t)p+2] = B;
}

extern "C" void kernel_launch(void* const* d_in, const int* in_sizes, int n_in,
                              void* d_out, int out_size, void* d_ws, size_t ws_size,
                              hipStream_t stream) {
    const float* means     = (const float*)d_in[0];
    const float* quats     = (const float*)d_in[1];
    const float* scales    = (const float*)d_in[2];
    const float* opacities = (const float*)d_in[3];
    const float* sh        = (const float*)d_in[4];
    const float* vm        = (const float*)d_in[5];
    const float* K         = (const float*)d_in[6];

    int N = in_sizes[0] / 3;   // gaussians (2048, problem-fixed <= MAXN)
    int P = out_size / 3;      // pixels (16384)
    int tiles = P / 64;        // 256 (8x8 tiles on 128x128)

    float*  sorted = (float*)d_ws;                               // (N+1)*12 floats
    float4* hdr    = (float4*)(sorted + (size_t)(N + 1) * 12);   // N float4
    float4* parts  = hdr + N;                                    // NLAYER*P float4

    prep_rank_kernel<<<(N + 7) / 8, 512, 0, stream>>>(
        means, quats, scales, opacities, sh, vm, K, sorted, hdr, N);
    render_kernel<<<tiles * NLAYER, 512, 0, stream>>>(
        sorted, hdr, parts, N, P);
    combine_kernel<<<(P + 255) / 256, 256, 0, stream>>>(
        parts, (float*)d_out, P);
}